// Round 20
// baseline (1273.343 us; speedup 1.0000x reference)
//
#include <hip/hip_runtime.h>

typedef unsigned short u16;
typedef unsigned int u32;
typedef __attribute__((ext_vector_type(8))) short shortx8;
typedef __attribute__((ext_vector_type(4))) float floatx4;
typedef __attribute__((ext_vector_type(4))) u32 uintx4;
typedef __attribute__((ext_vector_type(2))) u32 uintx2;

#define AS1 __attribute__((address_space(1)))
#define AS3 __attribute__((address_space(3)))

__device__ __forceinline__ float bf2f(u16 u) {
  return __builtin_bit_cast(float, ((u32)u) << 16);
}
__device__ __forceinline__ u16 f2bf(float f) {
  u32 i = __builtin_bit_cast(u32, f);
  u32 r = (i + 0x7fffu + ((i >> 16) & 1u)) >> 16;  // RNE
  return (u16)r;
}
__device__ __forceinline__ u16 f2bf_rtz(float f) {  // truncate: 1 op, for P>0
  return (u16)(__builtin_bit_cast(u32, f) >> 16);
}

// ---------------------------------------------------------------------------
// Fused prep: weight packing (r12-validated bodies) + enc_in, one launch.
// ---------------------------------------------------------------------------
__launch_bounds__(256)
__global__ void prep_all(const float* __restrict__ Wq, const float* __restrict__ Wk,
                         const float* __restrict__ Wv, const float* __restrict__ Wo,
                         const float* __restrict__ W1, const float* __restrict__ W2,
                         const float* __restrict__ bq, const float* __restrict__ bk,
                         const float* __restrict__ bv,
                         const float* __restrict__ x, const float* __restrict__ encW,
                         const float* __restrict__ encB,
                         u16* __restrict__ Bqkv, u16* __restrict__ Bwo,
                         u16* __restrict__ Bw1, u16* __restrict__ Bw2,
                         float* __restrict__ bias, u16* __restrict__ h) {
  __shared__ u16 T[64 * 72];
  const int blk = blockIdx.x;
  const int t = threadIdx.x;

  if (blk < 1536) {  // --- QKV pack: dst[l][h*64+d][k] ---
    const int which = blk >> 9, r = blk & 511;
    const int kt = r & 15, y = r >> 4;
    const float* W = (which == 0) ? Wq : (which == 1) ? Wk : Wv;
    u16* dst = Bqkv + (size_t)which * 1048576;
    const int l = y >> 4, hh = y & 15;
    const int rr = t >> 2, cq = (t & 3) * 16;
    const float* src = W + ((size_t)y * 1024 + kt * 64 + rr) * 64 + cq;
#pragma unroll
    for (int e4 = 0; e4 < 4; ++e4) {
      float4 f = *(const float4*)(src + e4 * 4);
      T[(cq + e4 * 4 + 0) * 72 + rr] = f2bf(f.x);
      T[(cq + e4 * 4 + 1) * 72 + rr] = f2bf(f.y);
      T[(cq + e4 * 4 + 2) * 72 + rr] = f2bf(f.z);
      T[(cq + e4 * 4 + 3) * 72 + rr] = f2bf(f.w);
    }
    __syncthreads();
    const int dd = t >> 2, kq = (t & 3) * 16;
    u16* drow = dst + (size_t)l * 3145728 + ((size_t)hh * 64 + dd) * 1024 + kt * 64 + kq;
    *(uintx4*)(drow) = *(const uintx4*)&T[dd * 72 + kq];
    *(uintx4*)(drow + 8) = *(const uintx4*)&T[dd * 72 + kq + 8];
  } else if (blk < 2048) {  // --- Wo pack (head-permuted): dst[l][n][h*64+d] ---
    const int r = blk - 1536;
    const int l = r >> 8, rx = r & 255;
    const int rt = rx >> 4, nt = rx & 15;
    const int rr = t >> 2, cq = (t & 3) * 16;
    const float* src = Wo + (size_t)l * 1048576 + (size_t)(rt * 64 + rr) * 1024 + nt * 64 + cq;
#pragma unroll
    for (int e4 = 0; e4 < 4; ++e4) {
      float4 f = *(const float4*)(src + e4 * 4);
      T[(cq + e4 * 4 + 0) * 72 + rr] = f2bf(f.x);
      T[(cq + e4 * 4 + 1) * 72 + rr] = f2bf(f.y);
      T[(cq + e4 * 4 + 2) * 72 + rr] = f2bf(f.z);
      T[(cq + e4 * 4 + 3) * 72 + rr] = f2bf(f.w);
    }
    __syncthreads();
    const int hh = t & 15;
#pragma unroll
    for (int pass = 0; pass < 4; ++pass) {
      const int nl = pass * 16 + (t >> 4);
      uintx2 pk;
      u16 v0 = T[nl * 72 + 0 * 16 + hh], v1 = T[nl * 72 + 1 * 16 + hh];
      u16 v2 = T[nl * 72 + 2 * 16 + hh], v3 = T[nl * 72 + 3 * 16 + hh];
      pk[0] = (u32)v0 | ((u32)v1 << 16);
      pk[1] = (u32)v2 | ((u32)v3 << 16);
      *(uintx2*)&Bwo[(size_t)l * 1048576 + (size_t)(nt * 64 + nl) * 1024 + hh * 64 + rt * 4] = pk;
    }
  } else if (blk < 3072) {  // --- W1 / W2 plain transpose: dst[l][n][k] ---
    const int job = (blk - 2048) >> 9;  // 0 = W1, 1 = W2
    const int r = (blk - 2048) & 511;
    const float* W = job == 0 ? W1 : W2;
    u16* dst = job == 0 ? Bw1 : Bw2;
    const int l = r >> 8, rx = r & 255;
    const int ct = rx & 15, rt = rx >> 4;
    const int rr = t >> 2, cq = (t & 3) * 16;
    const float* src = W + (size_t)l * 1048576 + (size_t)(rt * 64 + rr) * 1024 + ct * 64 + cq;
#pragma unroll
    for (int e4 = 0; e4 < 4; ++e4) {
      float4 f = *(const float4*)(src + e4 * 4);
      T[(cq + e4 * 4 + 0) * 72 + rr] = f2bf(f.x);
      T[(cq + e4 * 4 + 1) * 72 + rr] = f2bf(f.y);
      T[(cq + e4 * 4 + 2) * 72 + rr] = f2bf(f.z);
      T[(cq + e4 * 4 + 3) * 72 + rr] = f2bf(f.w);
    }
    __syncthreads();
    const int cc = t >> 2, rq = (t & 3) * 16;
    u16* drow = dst + (size_t)l * 1048576 + (size_t)(ct * 64 + cc) * 1024 + rt * 64 + rq;
    *(uintx4*)(drow) = *(const uintx4*)&T[cc * 72 + rq];
    *(uintx4*)(drow + 8) = *(const uintx4*)&T[cc * 72 + rq + 8];
  } else if (blk < 3096) {  // --- bias gather ---
    const int i = (blk - 3072) * 256 + t;  // [0, 6144)
    const int l = i / 3072, n = i % 3072;
    const int which = n >> 10, nn = n & 1023;
    const float* s = (which == 0) ? bq : (which == 1) ? bk : bv;
    bias[i] = s[l * 1024 + nn];
  } else {  // --- enc_in: 8 outputs/thread, 16B stores ---
    const size_t i = (size_t)(blk - 3096) * 256 + t;  // 19200*128
    const int m = (int)(i >> 7), nq = (int)((i & 127) << 3);
    const float* xr = x + (size_t)m * 9;
    float xv[9];
#pragma unroll
    for (int f = 0; f < 9; ++f) xv[f] = xr[f];
    u16 ov[8];
#pragma unroll
    for (int e = 0; e < 8; ++e) {
      float acc = encB[nq + e];
#pragma unroll
      for (int f = 0; f < 9; ++f) acc += xv[f] * encW[f * 1024 + nq + e];
      ov[e] = f2bf(acc);
    }
    *(uintx4*)&h[(size_t)m * 1024 + nq] = *(const uintx4*)ov;
  }
}

// ---------------------------------------------------------------------------
// WIDE GEMM (r9/r15-proven, FINAL geometry): 128x256, BK=64, 8 waves, 512 thr.
// EPI: 0 = bias; 1 = bias + residual R; 2 = bias + ELU;
//      3 = bias + q-column 0.125 scale, C stored NONTEMPORAL (write-allocate
//          theory: 135MB of QKV's 180MB FETCH is C-line allocation; consumer
//          (attn) re-reads from HBM anyway, so bypass costs ~nothing)
// ---------------------------------------------------------------------------
template <int EPI>
__launch_bounds__(512)
__global__ void gemm_bt_wide(const u16* __restrict__ A, int lda,
                             const u16* __restrict__ Bt,
                             const float* __restrict__ bias,
                             const u16* __restrict__ R, int ldr,
                             u16* __restrict__ C, int ldc) {
  constexpr int K = 1024;
  __shared__ u16 As[128 * 64];
  __shared__ u16 Bs[256 * 64];
  const int tid = threadIdx.x;
  const int lane = tid & 63;
  const int w = tid >> 6;
  const int wr = w >> 2, wc = w & 3;
  const int m0 = blockIdx.y * 128, n0 = blockIdx.x * 256;

  floatx4 acc[4][4];
#pragma unroll
  for (int i = 0; i < 4; ++i)
#pragma unroll
    for (int j = 0; j < 4; ++j) acc[i][j] = (floatx4){0.f, 0.f, 0.f, 0.f};

  const u16* Ab = A + (size_t)m0 * lda;
  const u16* Bb = Bt + (size_t)n0 * K;

  for (int k0 = 0; k0 < K; k0 += 64) {
#pragma unroll
    for (int p = 0; p < 2; ++p) {
      const int o = p * 8192 + tid * 16;
      const int row = o >> 7;
      const int ke = (o & 127) >> 1;
      __builtin_amdgcn_global_load_lds((const AS1 void*)(Ab + (size_t)row * lda + (k0 + ke)),
                                       (AS3 void*)((char*)As + o), 16, 0, 0);
    }
#pragma unroll
    for (int p = 0; p < 4; ++p) {
      const int o = p * 8192 + tid * 16;
      const int row = o >> 7;
      const int ke = (o & 127) >> 1;
      __builtin_amdgcn_global_load_lds((const AS1 void*)(Bb + (size_t)row * K + (k0 + ke)),
                                       (AS3 void*)((char*)Bs + o), 16, 0, 0);
    }
    __syncthreads();
#pragma unroll
    for (int ks = 0; ks < 2; ++ks) {
      shortx8 af[4], bfr[4];
#pragma unroll
      for (int i = 0; i < 4; ++i) {
        const int ar = wr * 64 + i * 16 + (lane & 15);
        af[i] = *(const shortx8*)&As[ar * 64 + ks * 32 + (lane >> 4) * 8];
        const int br = wc * 64 + i * 16 + (lane & 15);
        bfr[i] = *(const shortx8*)&Bs[br * 64 + ks * 32 + (lane >> 4) * 8];
      }
#pragma unroll
      for (int i = 0; i < 4; ++i)
#pragma unroll
        for (int j = 0; j < 4; ++j)
          acc[i][j] = __builtin_amdgcn_mfma_f32_16x16x32_bf16(af[i], bfr[j], acc[i][j], 0, 0, 0);
    }
    __syncthreads();
  }

  const int lr = (lane >> 4) * 4, lc = lane & 15;
#pragma unroll
  for (int i = 0; i < 4; ++i) {
#pragma unroll
    for (int j = 0; j < 4; ++j) {
      const int col = n0 + wc * 64 + j * 16 + lc;
      const float bv = bias[col];
      const bool qcol = (EPI == 3) && (col < 1024);
#pragma unroll
      for (int r = 0; r < 4; ++r) {
        const int row = m0 + wr * 64 + i * 16 + lr + r;
        float v = acc[i][j][r] + bv;
        if (EPI == 1) v += bf2f(R[(size_t)row * ldr + col]);
        if (EPI == 2) v = v > 0.f ? v : expm1f(v);
        if (EPI == 3) {
          if (qcol) v *= 0.125f;
          __builtin_nontemporal_store(f2bf(v), &C[(size_t)row * ldc + col]);
        } else {
          C[(size_t)row * ldc + col] = f2bf(v);
        }
      }
    }
  }
}

// ---------------------------------------------------------------------------
// MFMA flash attention — r17/r19-proven 4-wave version, T14 async-STAGE.
// ---------------------------------------------------------------------------
__launch_bounds__(256)
__global__ void attn_mfma(const u16* __restrict__ qkv, u16* __restrict__ aout) {
  const int qt = blockIdx.x, bh = blockIdx.y;
  const int b = bh >> 4, h = bh & 15;
  const int tid = threadIdx.x, lane = tid & 63, w = tid >> 6;
  const int g = lane >> 4, lq = lane & 15;

  __shared__ u16 K_ld[128 * 72];
  __shared__ u16 Vt[64 * 136];
  __shared__ u16 P_ld[4][16 * 136];

  const size_t bbase = (size_t)b * 600 * 3072;
  const int q0 = qt * 128 + w * 32;
  const int tloc = tid >> 1, dhalf = (tid & 1) * 32;
  const int dq = w * 16;

  shortx8 aq[2][2];
#pragma unroll
  for (int sub = 0; sub < 2; ++sub) {
    const int s = q0 + sub * 16 + lq;
    if (s < 600) {
      const u16* qp = qkv + bbase + (size_t)s * 3072 + h * 64 + g * 8;
      aq[sub][0] = *(const shortx8*)qp;
      aq[sub][1] = *(const shortx8*)(qp + 32);
    } else {
      aq[sub][0] = (shortx8){0, 0, 0, 0, 0, 0, 0, 0};
      aq[sub][1] = (shortx8){0, 0, 0, 0, 0, 0, 0, 0};
    }
  }

  floatx4 Oa[2][4];
  float m[2][4], l[2][4];
#pragma unroll
  for (int sub = 0; sub < 2; ++sub) {
#pragma unroll
    for (int db = 0; db < 4; ++db) Oa[sub][db] = (floatx4){0.f, 0.f, 0.f, 0.f};
#pragma unroll
    for (int r = 0; r < 4; ++r) { m[sub][r] = -1e30f; l[sub][r] = 0.f; }
  }

  uintx4 kreg[4];
  shortx8 vra, vrb, vrc, vrd;

  auto LOADC = [&](int ch) {
    const int t0 = ch * 128;
    if (ch < 4) {
      const u16* kp = qkv + bbase + (size_t)(t0 + tloc) * 3072 + 1024 + h * 64 + dhalf;
#pragma unroll
      for (int c = 0; c < 4; ++c) kreg[c] = *(const uintx4*)(kp + c * 8);
      const u16* vp0 = qkv + bbase + (size_t)(t0 + lane * 2) * 3072 + 2048 + h * 64 + dq;
      vra = *(const shortx8*)vp0;
      vrb = *(const shortx8*)(vp0 + 8);
      vrc = *(const shortx8*)(vp0 + 3072);
      vrd = *(const shortx8*)(vp0 + 3072 + 8);
    } else {
      const int tg = t0 + tloc;
      if (tg < 600) {
        const u16* kp = qkv + bbase + (size_t)tg * 3072 + 1024 + h * 64 + dhalf;
#pragma unroll
        for (int c = 0; c < 4; ++c) kreg[c] = *(const uintx4*)(kp + c * 8);
      } else {
#pragma unroll
        for (int c = 0; c < 4; ++c) kreg[c] = (uintx4){0, 0, 0, 0};
      }
      const int tp = t0 + lane * 2;
      if (tp < 600) {
        const u16* vp = qkv + bbase + (size_t)tp * 3072 + 2048 + h * 64 + dq;
        vra = *(const shortx8*)vp;
        vrb = *(const shortx8*)(vp + 8);
      } else {
        vra = (shortx8){0, 0, 0, 0, 0, 0, 0, 0};
        vrb = vra;
      }
      if (tp + 1 < 600) {
        const u16* vp = qkv + bbase + (size_t)(tp + 1) * 3072 + 2048 + h * 64 + dq;
        vrc = *(const shortx8*)vp;
        vrd = *(const shortx8*)(vp + 8);
      } else {
        vrc = (shortx8){0, 0, 0, 0, 0, 0, 0, 0};
        vrd = vrc;
      }
    }
  };
  auto WRITEC = [&]() {
#pragma unroll
    for (int c = 0; c < 4; ++c)
      *(uintx4*)&K_ld[tloc * 72 + dhalf + c * 8] = kreg[c];
#pragma unroll
    for (int e = 0; e < 8; ++e) {
      *(u32*)&Vt[(dq + e) * 136 + lane * 2] =
          (u32)(u16)vra[e] | ((u32)(u16)vrc[e] << 16);
      *(u32*)&Vt[(dq + 8 + e) * 136 + lane * 2] =
          (u32)(u16)vrb[e] | ((u32)(u16)vrd[e] << 16);
    }
  };

  LOADC(0);
  for (int ch = 0; ch < 5; ++ch) {
    const int t0 = ch * 128;
    __syncthreads();
    WRITEC();
    if (ch < 4) LOADC(ch + 1);
    __syncthreads();

#pragma unroll
    for (int sub = 0; sub < 2; ++sub) {
      floatx4 S[8];
      __builtin_amdgcn_s_setprio(1);
#pragma unroll
      for (int jb = 0; jb < 8; ++jb) {
        S[jb] = (floatx4){0.f, 0.f, 0.f, 0.f};
#pragma unroll
        for (int ks = 0; ks < 2; ++ks) {
          shortx8 bk = *(const shortx8*)&K_ld[(jb * 16 + lq) * 72 + ks * 32 + g * 8];
          S[jb] = __builtin_amdgcn_mfma_f32_16x16x32_bf16(aq[sub][ks], bk, S[jb], 0, 0, 0);
        }
      }
      __builtin_amdgcn_s_setprio(0);
      if (ch == 4) {
#pragma unroll
        for (int jb = 0; jb < 8; ++jb) {
          const bool ok = (t0 + jb * 16 + lq) < 600;
#pragma unroll
          for (int r = 0; r < 4; ++r) S[jb][r] = ok ? S[jb][r] : -1e30f;
        }
      }

      float vmax[4];
      bool need = false;
#pragma unroll
      for (int r = 0; r < 4; ++r) {
        const float v01 = fmaxf(S[0][r], S[1][r]);
        const float v23 = fmaxf(S[2][r], S[3][r]);
        const float v45 = fmaxf(S[4][r], S[5][r]);
        const float v67 = fmaxf(S[6][r], S[7][r]);
        float v = fmaxf(fmaxf(v01, v23), fmaxf(v45, v67));
        v = fmaxf(v, __shfl_xor(v, 1));
        v = fmaxf(v, __shfl_xor(v, 2));
        v = fmaxf(v, __shfl_xor(v, 4));
        v = fmaxf(v, __shfl_xor(v, 8));
        vmax[r] = v;
        need |= (v > m[sub][r] + 8.0f);
      }
      if (__any(need ? 1 : 0)) {
#pragma unroll
        for (int r = 0; r < 4; ++r) {
          const float mn = fmaxf(m[sub][r], vmax[r]);
          const float sc = __expf(m[sub][r] - mn);
          m[sub][r] = mn;
          l[sub][r] *= sc;
#pragma unroll
          for (int db = 0; db < 4; ++db) Oa[sub][db][r] *= sc;
        }
      }

      float sums[4] = {0.f, 0.f, 0.f, 0.f};
#pragma unroll
      for (int jb = 0; jb < 8; ++jb)
#pragma unroll
        for (int r = 0; r < 4; ++r) {
          const float p = __expf(S[jb][r] - m[sub][r]);
          sums[r] += p;
          P_ld[w][(g * 4 + r) * 136 + jb * 16 + lq] = f2bf_rtz(p);
        }
#pragma unroll
      for (int r = 0; r < 4; ++r) {
        float v = sums[r];
        v += __shfl_xor(v, 1);
        v += __shfl_xor(v, 2);
        v += __shfl_xor(v, 4);
        v += __shfl_xor(v, 8);
        l[sub][r] += v;
      }

      __builtin_amdgcn_s_setprio(1);
#pragma unroll
      for (int ks = 0; ks < 4; ++ks) {
        shortx8 ap = *(const shortx8*)&P_ld[w][lq * 136 + ks * 32 + g * 8];
#pragma unroll
        for (int db = 0; db < 4; ++db) {
          shortx8 bv = *(const shortx8*)&Vt[(db * 16 + lq) * 136 + ks * 32 + g * 8];
          Oa[sub][db] = __builtin_amdgcn_mfma_f32_16x16x32_bf16(ap, bv, Oa[sub][db], 0, 0, 0);
        }
      }
      __builtin_amdgcn_s_setprio(0);
    }
  }

#pragma unroll
  for (int sub = 0; sub < 2; ++sub) {
#pragma unroll
    for (int r = 0; r < 4; ++r) {
      const int sg = q0 + sub * 16 + g * 4 + r;
      if (sg < 600) {
        const float inv = 1.f / l[sub][r];
        u16* orow = aout + ((size_t)(b * 600 + sg)) * 1024 + h * 64;
#pragma unroll
        for (int db = 0; db < 4; ++db)
          orow[db * 16 + lq] = f2bf(Oa[sub][db][r] * inv);
      }
    }
  }
}

// ---------------------------------------------------------------------------
// LayerNorm over 1024 (strided rows): one block per row, biased var, eps 1e-5.
// ---------------------------------------------------------------------------
__launch_bounds__(256)
__global__ void ln_kernel(const u16* __restrict__ y, int ldy,
                          const float* __restrict__ g, const float* __restrict__ be,
                          u16* __restrict__ o, int ldo) {
  const int row = blockIdx.x, tid = threadIdx.x;
  const int lane = tid & 63, wv = tid >> 6;
  const u16* yr = y + (size_t)row * ldy;
  const int c = tid * 4;
  const uintx2 yv = *(const uintx2*)&yr[c];
  float v0 = bf2f((u16)(yv[0] & 0xffffu)), v1 = bf2f((u16)(yv[0] >> 16));
  float v2 = bf2f((u16)(yv[1] & 0xffffu)), v3 = bf2f((u16)(yv[1] >> 16));
  float s = v0 + v1 + v2 + v3;
  float q = v0 * v0 + v1 * v1 + v2 * v2 + v3 * v3;
#pragma unroll
  for (int m = 32; m; m >>= 1) {
    s += __shfl_xor(s, m);
    q += __shfl_xor(q, m);
  }
  __shared__ float red[2][4];
  if (lane == 0) {
    red[0][wv] = s;
    red[1][wv] = q;
  }
  __syncthreads();
  s = red[0][0] + red[0][1] + red[0][2] + red[0][3];
  q = red[1][0] + red[1][1] + red[1][2] + red[1][3];
  const float mu = s * (1.f / 1024.f);
  const float var = q * (1.f / 1024.f) - mu * mu;
  const float rstd = rsqrtf(var + 1e-5f);
  const float4 gv = *(const float4*)&g[c];
  const float4 bev = *(const float4*)&be[c];
  const float o0 = (v0 - mu) * rstd * gv.x + bev.x;
  const float o1 = (v1 - mu) * rstd * gv.y + bev.y;
  const float o2 = (v2 - mu) * rstd * gv.z + bev.z;
  const float o3 = (v3 - mu) * rstd * gv.w + bev.w;
  uintx2 ov;
  ov[0] = (u32)f2bf(o0) | ((u32)f2bf(o1) << 16);
  ov[1] = (u32)f2bf(o2) | ((u32)f2bf(o3) << 16);
  *(uintx2*)&o[(size_t)row * ldo + c] = ov;
}

// ---------------------------------------------------------------------------
// out: out[m][f] = h[m][:] . outW[:][f] + outb[f], f<9. One wave per row. fp32 out.
// ---------------------------------------------------------------------------
__launch_bounds__(256)
__global__ void out_kernel(const u16* __restrict__ h, const float* __restrict__ W,
                           const float* __restrict__ bias, float* __restrict__ out) {
  const int m = blockIdx.x * 4 + (threadIdx.x >> 6);
  const int lane = threadIdx.x & 63;
  float acc[9];
#pragma unroll
  for (int f = 0; f < 9; ++f) acc[f] = 0.f;
  const u16* hr = h + (size_t)m * 1024;
#pragma unroll 4
  for (int j = 0; j < 16; ++j) {
    const int k = lane + j * 64;
    const float hv = bf2f(hr[k]);
    const float* wr = W + (size_t)k * 9;
#pragma unroll
    for (int f = 0; f < 9; ++f) acc[f] += hv * wr[f];
  }
#pragma unroll
  for (int f = 0; f < 9; ++f)
#pragma unroll
    for (int mm = 32; mm; mm >>= 1) acc[f] += __shfl_xor(acc[f], mm);
  if (lane < 9) out[(size_t)m * 9 + lane] = acc[lane] + bias[lane];
}

// ---------------------------------------------------------------------------
extern "C" void kernel_launch(void* const* d_in, const int* in_sizes, int n_in,
                              void* d_out, int out_size, void* d_ws, size_t ws_size,
                              hipStream_t stream) {
  (void)in_sizes; (void)n_in; (void)out_size; (void)ws_size;
  const float* x     = (const float*)d_in[0];
  const float* encW  = (const float*)d_in[1];
  const float* encB  = (const float*)d_in[2];
  const float* Wq    = (const float*)d_in[3];
  const float* bq    = (const float*)d_in[4];
  const float* Wk    = (const float*)d_in[5];
  const float* bk    = (const float*)d_in[6];
  const float* Wv    = (const float*)d_in[7];
  const float* bv    = (const float*)d_in[8];
  const float* Wo    = (const float*)d_in[9];
  const float* bo    = (const float*)d_in[10];
  const float* W1    = (const float*)d_in[11];
  const float* b1    = (const float*)d_in[12];
  const float* W2    = (const float*)d_in[13];
  const float* b2    = (const float*)d_in[14];
  const float* ln1w  = (const float*)d_in[15];
  const float* ln1b  = (const float*)d_in[16];
  const float* ln2w  = (const float*)d_in[17];
  const float* ln2b  = (const float*)d_in[18];
  const float* outW  = (const float*)d_in[19];
  const float* outB  = (const float*)d_in[20];
  float* out = (float*)d_out;

  char* ws = (char*)d_ws;
  size_t off = 0;
  auto alloc = [&](size_t bytes) -> void* {
    void* p = ws + off;
    off += (bytes + 255) & ~(size_t)255;
    return p;
  };
  u16* h    = (u16*)alloc(19660800ull * 2);   // [19200][1024]
  u16* qkv  = (u16*)alloc(58982400ull * 2);   // [19200][3072]
  u16* abuf = (u16*)alloc(19660800ull * 2);   // ctx [19200][1024] (h*64+d layout)
  u16* Bqkv = (u16*)alloc(6291456ull * 2);    // [2][3072][1024]
  u16* Bwo  = (u16*)alloc(2097152ull * 2);    // [2][1024][1024] permuted-transposed
  u16* Bw1  = (u16*)alloc(2097152ull * 2);
  u16* Bw2  = (u16*)alloc(2097152ull * 2);
  float* bqkv = (float*)alloc(6144ull * 4);   // [2][3072] fp32
  // column-slot aliases inside qkv (stride 3072), reusing dead q/k/v slots:
  u16* ybuf = qkv;          // q-slot: Wo-gemm output (q dead after attention)
  u16* x1   = qkv + 1024;   // k-slot: ln1 output
  u16* mid  = qkv + 2048;   // v-slot: fc2/ELU output
  u16* y2   = abuf;         // dense: fc1 output (+x1 residual); abuf dead by then

  prep_all<<<12696, 256, 0, stream>>>(Wq, Wk, Wv, Wo, W1, W2, bq, bk, bv,
                                      x, encW, encB,
                                      Bqkv, Bwo, Bw1, Bw2, bqkv, h);

  for (int l = 0; l < 2; ++l) {
    gemm_bt_wide<3><<<dim3(12, 150), 512, 0, stream>>>(
        h, 1024, Bqkv + (size_t)l * 3145728, bqkv + l * 3072, nullptr, 0, qkv, 3072);
    attn_mfma<<<dim3(5, 512), 256, 0, stream>>>(qkv, abuf);
    gemm_bt_wide<1><<<dim3(4, 150), 512, 0, stream>>>(
        abuf, 1024, Bwo + (size_t)l * 1048576, bo + l * 1024, h, 1024, ybuf, 3072);
    ln_kernel<<<19200, 256, 0, stream>>>(ybuf, 3072, ln1w + l * 1024, ln1b + l * 1024, x1, 3072);
    gemm_bt_wide<2><<<dim3(4, 150), 512, 0, stream>>>(
        x1, 3072, Bw2 + (size_t)l * 1048576, b2 + l * 1024, nullptr, 0, mid, 3072);
    gemm_bt_wide<1><<<dim3(4, 150), 512, 0, stream>>>(
        mid, 3072, Bw1 + (size_t)l * 1048576, b1 + l * 1024, x1, 3072, y2, 1024);
    ln_kernel<<<19200, 256, 0, stream>>>(y2, 1024, ln2w + l * 1024, ln2b + l * 1024, h, 1024);
  }
  out_kernel<<<4800, 256, 0, stream>>>(h, outW, outB, out);
}

// Round 21
// 1223.710 us; speedup vs baseline: 1.0406x; 1.0406x over previous
//
#include <hip/hip_runtime.h>

typedef unsigned short u16;
typedef unsigned int u32;
typedef __attribute__((ext_vector_type(8))) short shortx8;
typedef __attribute__((ext_vector_type(4))) float floatx4;
typedef __attribute__((ext_vector_type(4))) u32 uintx4;
typedef __attribute__((ext_vector_type(2))) u32 uintx2;

#define AS1 __attribute__((address_space(1)))
#define AS3 __attribute__((address_space(3)))

__device__ __forceinline__ float bf2f(u16 u) {
  return __builtin_bit_cast(float, ((u32)u) << 16);
}
__device__ __forceinline__ u16 f2bf(float f) {
  u32 i = __builtin_bit_cast(u32, f);
  u32 r = (i + 0x7fffu + ((i >> 16) & 1u)) >> 16;  // RNE
  return (u16)r;
}
__device__ __forceinline__ u16 f2bf_rtz(float f) {  // truncate: 1 op, for P>0
  return (u16)(__builtin_bit_cast(u32, f) >> 16);
}

// ---------------------------------------------------------------------------
// Fused prep: weight packing (r12-validated bodies) + enc_in, one launch.
// ---------------------------------------------------------------------------
__launch_bounds__(256)
__global__ void prep_all(const float* __restrict__ Wq, const float* __restrict__ Wk,
                         const float* __restrict__ Wv, const float* __restrict__ Wo,
                         const float* __restrict__ W1, const float* __restrict__ W2,
                         const float* __restrict__ bq, const float* __restrict__ bk,
                         const float* __restrict__ bv,
                         const float* __restrict__ x, const float* __restrict__ encW,
                         const float* __restrict__ encB,
                         u16* __restrict__ Bqkv, u16* __restrict__ Bwo,
                         u16* __restrict__ Bw1, u16* __restrict__ Bw2,
                         float* __restrict__ bias, u16* __restrict__ h) {
  __shared__ u16 T[64 * 72];
  const int blk = blockIdx.x;
  const int t = threadIdx.x;

  if (blk < 1536) {  // --- QKV pack: dst[l][h*64+d][k] ---
    const int which = blk >> 9, r = blk & 511;
    const int kt = r & 15, y = r >> 4;
    const float* W = (which == 0) ? Wq : (which == 1) ? Wk : Wv;
    u16* dst = Bqkv + (size_t)which * 1048576;
    const int l = y >> 4, hh = y & 15;
    const int rr = t >> 2, cq = (t & 3) * 16;
    const float* src = W + ((size_t)y * 1024 + kt * 64 + rr) * 64 + cq;
#pragma unroll
    for (int e4 = 0; e4 < 4; ++e4) {
      float4 f = *(const float4*)(src + e4 * 4);
      T[(cq + e4 * 4 + 0) * 72 + rr] = f2bf(f.x);
      T[(cq + e4 * 4 + 1) * 72 + rr] = f2bf(f.y);
      T[(cq + e4 * 4 + 2) * 72 + rr] = f2bf(f.z);
      T[(cq + e4 * 4 + 3) * 72 + rr] = f2bf(f.w);
    }
    __syncthreads();
    const int dd = t >> 2, kq = (t & 3) * 16;
    u16* drow = dst + (size_t)l * 3145728 + ((size_t)hh * 64 + dd) * 1024 + kt * 64 + kq;
    *(uintx4*)(drow) = *(const uintx4*)&T[dd * 72 + kq];
    *(uintx4*)(drow + 8) = *(const uintx4*)&T[dd * 72 + kq + 8];
  } else if (blk < 2048) {  // --- Wo pack (head-permuted): dst[l][n][h*64+d] ---
    const int r = blk - 1536;
    const int l = r >> 8, rx = r & 255;
    const int rt = rx >> 4, nt = rx & 15;
    const int rr = t >> 2, cq = (t & 3) * 16;
    const float* src = Wo + (size_t)l * 1048576 + (size_t)(rt * 64 + rr) * 1024 + nt * 64 + cq;
#pragma unroll
    for (int e4 = 0; e4 < 4; ++e4) {
      float4 f = *(const float4*)(src + e4 * 4);
      T[(cq + e4 * 4 + 0) * 72 + rr] = f2bf(f.x);
      T[(cq + e4 * 4 + 1) * 72 + rr] = f2bf(f.y);
      T[(cq + e4 * 4 + 2) * 72 + rr] = f2bf(f.z);
      T[(cq + e4 * 4 + 3) * 72 + rr] = f2bf(f.w);
    }
    __syncthreads();
    const int hh = t & 15;
#pragma unroll
    for (int pass = 0; pass < 4; ++pass) {
      const int nl = pass * 16 + (t >> 4);
      uintx2 pk;
      u16 v0 = T[nl * 72 + 0 * 16 + hh], v1 = T[nl * 72 + 1 * 16 + hh];
      u16 v2 = T[nl * 72 + 2 * 16 + hh], v3 = T[nl * 72 + 3 * 16 + hh];
      pk[0] = (u32)v0 | ((u32)v1 << 16);
      pk[1] = (u32)v2 | ((u32)v3 << 16);
      *(uintx2*)&Bwo[(size_t)l * 1048576 + (size_t)(nt * 64 + nl) * 1024 + hh * 64 + rt * 4] = pk;
    }
  } else if (blk < 3072) {  // --- W1 / W2 plain transpose: dst[l][n][k] ---
    const int job = (blk - 2048) >> 9;  // 0 = W1, 1 = W2
    const int r = (blk - 2048) & 511;
    const float* W = job == 0 ? W1 : W2;
    u16* dst = job == 0 ? Bw1 : Bw2;
    const int l = r >> 8, rx = r & 255;
    const int ct = rx & 15, rt = rx >> 4;
    const int rr = t >> 2, cq = (t & 3) * 16;
    const float* src = W + (size_t)l * 1048576 + (size_t)(rt * 64 + rr) * 1024 + ct * 64 + cq;
#pragma unroll
    for (int e4 = 0; e4 < 4; ++e4) {
      float4 f = *(const float4*)(src + e4 * 4);
      T[(cq + e4 * 4 + 0) * 72 + rr] = f2bf(f.x);
      T[(cq + e4 * 4 + 1) * 72 + rr] = f2bf(f.y);
      T[(cq + e4 * 4 + 2) * 72 + rr] = f2bf(f.z);
      T[(cq + e4 * 4 + 3) * 72 + rr] = f2bf(f.w);
    }
    __syncthreads();
    const int cc = t >> 2, rq = (t & 3) * 16;
    u16* drow = dst + (size_t)l * 1048576 + (size_t)(ct * 64 + cc) * 1024 + rt * 64 + rq;
    *(uintx4*)(drow) = *(const uintx4*)&T[cc * 72 + rq];
    *(uintx4*)(drow + 8) = *(const uintx4*)&T[cc * 72 + rq + 8];
  } else if (blk < 3096) {  // --- bias gather ---
    const int i = (blk - 3072) * 256 + t;  // [0, 6144)
    const int l = i / 3072, n = i % 3072;
    const int which = n >> 10, nn = n & 1023;
    const float* s = (which == 0) ? bq : (which == 1) ? bk : bv;
    bias[i] = s[l * 1024 + nn];
  } else {  // --- enc_in: 8 outputs/thread, 16B stores ---
    const size_t i = (size_t)(blk - 3096) * 256 + t;  // 19200*128
    const int m = (int)(i >> 7), nq = (int)((i & 127) << 3);
    const float* xr = x + (size_t)m * 9;
    float xv[9];
#pragma unroll
    for (int f = 0; f < 9; ++f) xv[f] = xr[f];
    u16 ov[8];
#pragma unroll
    for (int e = 0; e < 8; ++e) {
      float acc = encB[nq + e];
#pragma unroll
      for (int f = 0; f < 9; ++f) acc += xv[f] * encW[f * 1024 + nq + e];
      ov[e] = f2bf(acc);
    }
    *(uintx4*)&h[(size_t)m * 1024 + nq] = *(const uintx4*)ov;
  }
}

// ---------------------------------------------------------------------------
// WIDE GEMM (r9/r15-proven, FINAL geometry): 128x256, BK=64, 8 waves, 512 thr.
// EPI: 0 = bias; 1 = bias + residual R; 2 = bias + ELU;
//      3 = bias, then cols<1024 (q-slot) scaled 0.125 (softmax scale folded)
// r20 lesson: nontemporal C-stores REGRESSED (WRITE 115->250MB: L2 was
// coalescing partial-line u16 stores; NT write-through broke it). Normal
// stores restored.
// ---------------------------------------------------------------------------
template <int EPI>
__launch_bounds__(512)
__global__ void gemm_bt_wide(const u16* __restrict__ A, int lda,
                             const u16* __restrict__ Bt,
                             const float* __restrict__ bias,
                             const u16* __restrict__ R, int ldr,
                             u16* __restrict__ C, int ldc) {
  constexpr int K = 1024;
  __shared__ u16 As[128 * 64];
  __shared__ u16 Bs[256 * 64];
  const int tid = threadIdx.x;
  const int lane = tid & 63;
  const int w = tid >> 6;
  const int wr = w >> 2, wc = w & 3;
  const int m0 = blockIdx.y * 128, n0 = blockIdx.x * 256;

  floatx4 acc[4][4];
#pragma unroll
  for (int i = 0; i < 4; ++i)
#pragma unroll
    for (int j = 0; j < 4; ++j) acc[i][j] = (floatx4){0.f, 0.f, 0.f, 0.f};

  const u16* Ab = A + (size_t)m0 * lda;
  const u16* Bb = Bt + (size_t)n0 * K;

  for (int k0 = 0; k0 < K; k0 += 64) {
#pragma unroll
    for (int p = 0; p < 2; ++p) {
      const int o = p * 8192 + tid * 16;
      const int row = o >> 7;
      const int ke = (o & 127) >> 1;
      __builtin_amdgcn_global_load_lds((const AS1 void*)(Ab + (size_t)row * lda + (k0 + ke)),
                                       (AS3 void*)((char*)As + o), 16, 0, 0);
    }
#pragma unroll
    for (int p = 0; p < 4; ++p) {
      const int o = p * 8192 + tid * 16;
      const int row = o >> 7;
      const int ke = (o & 127) >> 1;
      __builtin_amdgcn_global_load_lds((const AS1 void*)(Bb + (size_t)row * K + (k0 + ke)),
                                       (AS3 void*)((char*)Bs + o), 16, 0, 0);
    }
    __syncthreads();
#pragma unroll
    for (int ks = 0; ks < 2; ++ks) {
      shortx8 af[4], bfr[4];
#pragma unroll
      for (int i = 0; i < 4; ++i) {
        const int ar = wr * 64 + i * 16 + (lane & 15);
        af[i] = *(const shortx8*)&As[ar * 64 + ks * 32 + (lane >> 4) * 8];
        const int br = wc * 64 + i * 16 + (lane & 15);
        bfr[i] = *(const shortx8*)&Bs[br * 64 + ks * 32 + (lane >> 4) * 8];
      }
#pragma unroll
      for (int i = 0; i < 4; ++i)
#pragma unroll
        for (int j = 0; j < 4; ++j)
          acc[i][j] = __builtin_amdgcn_mfma_f32_16x16x32_bf16(af[i], bfr[j], acc[i][j], 0, 0, 0);
    }
    __syncthreads();
  }

  const int lr = (lane >> 4) * 4, lc = lane & 15;
#pragma unroll
  for (int i = 0; i < 4; ++i) {
#pragma unroll
    for (int j = 0; j < 4; ++j) {
      const int col = n0 + wc * 64 + j * 16 + lc;
      const float bv = bias[col];
      const bool qcol = (EPI == 3) && (col < 1024);
#pragma unroll
      for (int r = 0; r < 4; ++r) {
        const int row = m0 + wr * 64 + i * 16 + lr + r;
        float v = acc[i][j][r] + bv;
        if (EPI == 1) v += bf2f(R[(size_t)row * ldr + col]);
        if (EPI == 2) v = v > 0.f ? v : expm1f(v);
        if (EPI == 3 && qcol) v *= 0.125f;
        C[(size_t)row * ldc + col] = f2bf(v);
      }
    }
  }
}

// ---------------------------------------------------------------------------
// MFMA flash attention — r17/r19-proven 4-wave version, T14 async-STAGE.
// ---------------------------------------------------------------------------
__launch_bounds__(256)
__global__ void attn_mfma(const u16* __restrict__ qkv, u16* __restrict__ aout) {
  const int qt = blockIdx.x, bh = blockIdx.y;
  const int b = bh >> 4, h = bh & 15;
  const int tid = threadIdx.x, lane = tid & 63, w = tid >> 6;
  const int g = lane >> 4, lq = lane & 15;

  __shared__ u16 K_ld[128 * 72];
  __shared__ u16 Vt[64 * 136];
  __shared__ u16 P_ld[4][16 * 136];

  const size_t bbase = (size_t)b * 600 * 3072;
  const int q0 = qt * 128 + w * 32;
  const int tloc = tid >> 1, dhalf = (tid & 1) * 32;
  const int dq = w * 16;

  shortx8 aq[2][2];
#pragma unroll
  for (int sub = 0; sub < 2; ++sub) {
    const int s = q0 + sub * 16 + lq;
    if (s < 600) {
      const u16* qp = qkv + bbase + (size_t)s * 3072 + h * 64 + g * 8;
      aq[sub][0] = *(const shortx8*)qp;
      aq[sub][1] = *(const shortx8*)(qp + 32);
    } else {
      aq[sub][0] = (shortx8){0, 0, 0, 0, 0, 0, 0, 0};
      aq[sub][1] = (shortx8){0, 0, 0, 0, 0, 0, 0, 0};
    }
  }

  floatx4 Oa[2][4];
  float m[2][4], l[2][4];
#pragma unroll
  for (int sub = 0; sub < 2; ++sub) {
#pragma unroll
    for (int db = 0; db < 4; ++db) Oa[sub][db] = (floatx4){0.f, 0.f, 0.f, 0.f};
#pragma unroll
    for (int r = 0; r < 4; ++r) { m[sub][r] = -1e30f; l[sub][r] = 0.f; }
  }

  uintx4 kreg[4];
  shortx8 vra, vrb, vrc, vrd;

  auto LOADC = [&](int ch) {
    const int t0 = ch * 128;
    if (ch < 4) {
      const u16* kp = qkv + bbase + (size_t)(t0 + tloc) * 3072 + 1024 + h * 64 + dhalf;
#pragma unroll
      for (int c = 0; c < 4; ++c) kreg[c] = *(const uintx4*)(kp + c * 8);
      const u16* vp0 = qkv + bbase + (size_t)(t0 + lane * 2) * 3072 + 2048 + h * 64 + dq;
      vra = *(const shortx8*)vp0;
      vrb = *(const shortx8*)(vp0 + 8);
      vrc = *(const shortx8*)(vp0 + 3072);
      vrd = *(const shortx8*)(vp0 + 3072 + 8);
    } else {
      const int tg = t0 + tloc;
      if (tg < 600) {
        const u16* kp = qkv + bbase + (size_t)tg * 3072 + 1024 + h * 64 + dhalf;
#pragma unroll
        for (int c = 0; c < 4; ++c) kreg[c] = *(const uintx4*)(kp + c * 8);
      } else {
#pragma unroll
        for (int c = 0; c < 4; ++c) kreg[c] = (uintx4){0, 0, 0, 0};
      }
      const int tp = t0 + lane * 2;
      if (tp < 600) {
        const u16* vp = qkv + bbase + (size_t)tp * 3072 + 2048 + h * 64 + dq;
        vra = *(const shortx8*)vp;
        vrb = *(const shortx8*)(vp + 8);
      } else {
        vra = (shortx8){0, 0, 0, 0, 0, 0, 0, 0};
        vrb = vra;
      }
      if (tp + 1 < 600) {
        const u16* vp = qkv + bbase + (size_t)(tp + 1) * 3072 + 2048 + h * 64 + dq;
        vrc = *(const shortx8*)vp;
        vrd = *(const shortx8*)(vp + 8);
      } else {
        vrc = (shortx8){0, 0, 0, 0, 0, 0, 0, 0};
        vrd = vrc;
      }
    }
  };
  auto WRITEC = [&]() {
#pragma unroll
    for (int c = 0; c < 4; ++c)
      *(uintx4*)&K_ld[tloc * 72 + dhalf + c * 8] = kreg[c];
#pragma unroll
    for (int e = 0; e < 8; ++e) {
      *(u32*)&Vt[(dq + e) * 136 + lane * 2] =
          (u32)(u16)vra[e] | ((u32)(u16)vrc[e] << 16);
      *(u32*)&Vt[(dq + 8 + e) * 136 + lane * 2] =
          (u32)(u16)vrb[e] | ((u32)(u16)vrd[e] << 16);
    }
  };

  LOADC(0);
  for (int ch = 0; ch < 5; ++ch) {
    const int t0 = ch * 128;
    __syncthreads();
    WRITEC();
    if (ch < 4) LOADC(ch + 1);
    __syncthreads();

#pragma unroll
    for (int sub = 0; sub < 2; ++sub) {
      floatx4 S[8];
      __builtin_amdgcn_s_setprio(1);
#pragma unroll
      for (int jb = 0; jb < 8; ++jb) {
        S[jb] = (floatx4){0.f, 0.f, 0.f, 0.f};
#pragma unroll
        for (int ks = 0; ks < 2; ++ks) {
          shortx8 bk = *(const shortx8*)&K_ld[(jb * 16 + lq) * 72 + ks * 32 + g * 8];
          S[jb] = __builtin_amdgcn_mfma_f32_16x16x32_bf16(aq[sub][ks], bk, S[jb], 0, 0, 0);
        }
      }
      __builtin_amdgcn_s_setprio(0);
      if (ch == 4) {
#pragma unroll
        for (int jb = 0; jb < 8; ++jb) {
          const bool ok = (t0 + jb * 16 + lq) < 600;
#pragma unroll
          for (int r = 0; r < 4; ++r) S[jb][r] = ok ? S[jb][r] : -1e30f;
        }
      }

      float vmax[4];
      bool need = false;
#pragma unroll
      for (int r = 0; r < 4; ++r) {
        const float v01 = fmaxf(S[0][r], S[1][r]);
        const float v23 = fmaxf(S[2][r], S[3][r]);
        const float v45 = fmaxf(S[4][r], S[5][r]);
        const float v67 = fmaxf(S[6][r], S[7][r]);
        float v = fmaxf(fmaxf(v01, v23), fmaxf(v45, v67));
        v = fmaxf(v, __shfl_xor(v, 1));
        v = fmaxf(v, __shfl_xor(v, 2));
        v = fmaxf(v, __shfl_xor(v, 4));
        v = fmaxf(v, __shfl_xor(v, 8));
        vmax[r] = v;
        need |= (v > m[sub][r] + 8.0f);
      }
      if (__any(need ? 1 : 0)) {
#pragma unroll
        for (int r = 0; r < 4; ++r) {
          const float mn = fmaxf(m[sub][r], vmax[r]);
          const float sc = __expf(m[sub][r] - mn);
          m[sub][r] = mn;
          l[sub][r] *= sc;
#pragma unroll
          for (int db = 0; db < 4; ++db) Oa[sub][db][r] *= sc;
        }
      }

      float sums[4] = {0.f, 0.f, 0.f, 0.f};
#pragma unroll
      for (int jb = 0; jb < 8; ++jb)
#pragma unroll
        for (int r = 0; r < 4; ++r) {
          const float p = __expf(S[jb][r] - m[sub][r]);
          sums[r] += p;
          P_ld[w][(g * 4 + r) * 136 + jb * 16 + lq] = f2bf_rtz(p);
        }
#pragma unroll
      for (int r = 0; r < 4; ++r) {
        float v = sums[r];
        v += __shfl_xor(v, 1);
        v += __shfl_xor(v, 2);
        v += __shfl_xor(v, 4);
        v += __shfl_xor(v, 8);
        l[sub][r] += v;
      }

      __builtin_amdgcn_s_setprio(1);
#pragma unroll
      for (int ks = 0; ks < 4; ++ks) {
        shortx8 ap = *(const shortx8*)&P_ld[w][lq * 136 + ks * 32 + g * 8];
#pragma unroll
        for (int db = 0; db < 4; ++db) {
          shortx8 bv = *(const shortx8*)&Vt[(db * 16 + lq) * 136 + ks * 32 + g * 8];
          Oa[sub][db] = __builtin_amdgcn_mfma_f32_16x16x32_bf16(ap, bv, Oa[sub][db], 0, 0, 0);
        }
      }
      __builtin_amdgcn_s_setprio(0);
    }
  }

#pragma unroll
  for (int sub = 0; sub < 2; ++sub) {
#pragma unroll
    for (int r = 0; r < 4; ++r) {
      const int sg = q0 + sub * 16 + g * 4 + r;
      if (sg < 600) {
        const float inv = 1.f / l[sub][r];
        u16* orow = aout + ((size_t)(b * 600 + sg)) * 1024 + h * 64;
#pragma unroll
        for (int db = 0; db < 4; ++db)
          orow[db * 16 + lq] = f2bf(Oa[sub][db][r] * inv);
      }
    }
  }
}

// ---------------------------------------------------------------------------
// LayerNorm over 1024 (strided rows): one block per row, biased var, eps 1e-5.
// ---------------------------------------------------------------------------
__launch_bounds__(256)
__global__ void ln_kernel(const u16* __restrict__ y, int ldy,
                          const float* __restrict__ g, const float* __restrict__ be,
                          u16* __restrict__ o, int ldo) {
  const int row = blockIdx.x, tid = threadIdx.x;
  const int lane = tid & 63, wv = tid >> 6;
  const u16* yr = y + (size_t)row * ldy;
  const int c = tid * 4;
  const uintx2 yv = *(const uintx2*)&yr[c];
  float v0 = bf2f((u16)(yv[0] & 0xffffu)), v1 = bf2f((u16)(yv[0] >> 16));
  float v2 = bf2f((u16)(yv[1] & 0xffffu)), v3 = bf2f((u16)(yv[1] >> 16));
  float s = v0 + v1 + v2 + v3;
  float q = v0 * v0 + v1 * v1 + v2 * v2 + v3 * v3;
#pragma unroll
  for (int m = 32; m; m >>= 1) {
    s += __shfl_xor(s, m);
    q += __shfl_xor(q, m);
  }
  __shared__ float red[2][4];
  if (lane == 0) {
    red[0][wv] = s;
    red[1][wv] = q;
  }
  __syncthreads();
  s = red[0][0] + red[0][1] + red[0][2] + red[0][3];
  q = red[1][0] + red[1][1] + red[1][2] + red[1][3];
  const float mu = s * (1.f / 1024.f);
  const float var = q * (1.f / 1024.f) - mu * mu;
  const float rstd = rsqrtf(var + 1e-5f);
  const float4 gv = *(const float4*)&g[c];
  const float4 bev = *(const float4*)&be[c];
  const float o0 = (v0 - mu) * rstd * gv.x + bev.x;
  const float o1 = (v1 - mu) * rstd * gv.y + bev.y;
  const float o2 = (v2 - mu) * rstd * gv.z + bev.z;
  const float o3 = (v3 - mu) * rstd * gv.w + bev.w;
  uintx2 ov;
  ov[0] = (u32)f2bf(o0) | ((u32)f2bf(o1) << 16);
  ov[1] = (u32)f2bf(o2) | ((u32)f2bf(o3) << 16);
  *(uintx2*)&o[(size_t)row * ldo + c] = ov;
}

// ---------------------------------------------------------------------------
// out: out[m][f] = h[m][:] . outW[:][f] + outb[f], f<9. One wave per row. fp32 out.
// ---------------------------------------------------------------------------
__launch_bounds__(256)
__global__ void out_kernel(const u16* __restrict__ h, const float* __restrict__ W,
                           const float* __restrict__ bias, float* __restrict__ out) {
  const int m = blockIdx.x * 4 + (threadIdx.x >> 6);
  const int lane = threadIdx.x & 63;
  float acc[9];
#pragma unroll
  for (int f = 0; f < 9; ++f) acc[f] = 0.f;
  const u16* hr = h + (size_t)m * 1024;
#pragma unroll 4
  for (int j = 0; j < 16; ++j) {
    const int k = lane + j * 64;
    const float hv = bf2f(hr[k]);
    const float* wr = W + (size_t)k * 9;
#pragma unroll
    for (int f = 0; f < 9; ++f) acc[f] += hv * wr[f];
  }
#pragma unroll
  for (int f = 0; f < 9; ++f)
#pragma unroll
    for (int mm = 32; mm; mm >>= 1) acc[f] += __shfl_xor(acc[f], mm);
  if (lane < 9) out[(size_t)m * 9 + lane] = acc[lane] + bias[lane];
}

// ---------------------------------------------------------------------------
extern "C" void kernel_launch(void* const* d_in, const int* in_sizes, int n_in,
                              void* d_out, int out_size, void* d_ws, size_t ws_size,
                              hipStream_t stream) {
  (void)in_sizes; (void)n_in; (void)out_size; (void)ws_size;
  const float* x     = (const float*)d_in[0];
  const float* encW  = (const float*)d_in[1];
  const float* encB  = (const float*)d_in[2];
  const float* Wq    = (const float*)d_in[3];
  const float* bq    = (const float*)d_in[4];
  const float* Wk    = (const float*)d_in[5];
  const float* bk    = (const float*)d_in[6];
  const float* Wv    = (const float*)d_in[7];
  const float* bv    = (const float*)d_in[8];
  const float* Wo    = (const float*)d_in[9];
  const float* bo    = (const float*)d_in[10];
  const float* W1    = (const float*)d_in[11];
  const float* b1    = (const float*)d_in[12];
  const float* W2    = (const float*)d_in[13];
  const float* b2    = (const float*)d_in[14];
  const float* ln1w  = (const float*)d_in[15];
  const float* ln1b  = (const float*)d_in[16];
  const float* ln2w  = (const float*)d_in[17];
  const float* ln2b  = (const float*)d_in[18];
  const float* outW  = (const float*)d_in[19];
  const float* outB  = (const float*)d_in[20];
  float* out = (float*)d_out;

  char* ws = (char*)d_ws;
  size_t off = 0;
  auto alloc = [&](size_t bytes) -> void* {
    void* p = ws + off;
    off += (bytes + 255) & ~(size_t)255;
    return p;
  };
  u16* h    = (u16*)alloc(19660800ull * 2);   // [19200][1024]
  u16* qkv  = (u16*)alloc(58982400ull * 2);   // [19200][3072]
  u16* abuf = (u16*)alloc(19660800ull * 2);   // ctx [19200][1024] (h*64+d layout)
  u16* Bqkv = (u16*)alloc(6291456ull * 2);    // [2][3072][1024]
  u16* Bwo  = (u16*)alloc(2097152ull * 2);    // [2][1024][1024] permuted-transposed
  u16* Bw1  = (u16*)alloc(2097152ull * 2);
  u16* Bw2  = (u16*)alloc(2097152ull * 2);
  float* bqkv = (float*)alloc(6144ull * 4);   // [2][3072] fp32
  // column-slot aliases inside qkv (stride 3072), reusing dead q/k/v slots:
  u16* ybuf = qkv;          // q-slot: Wo-gemm output (q dead after attention)
  u16* x1   = qkv + 1024;   // k-slot: ln1 output
  u16* mid  = qkv + 2048;   // v-slot: fc2/ELU output
  u16* y2   = abuf;         // dense: fc1 output (+x1 residual); abuf dead by then

  prep_all<<<12696, 256, 0, stream>>>(Wq, Wk, Wv, Wo, W1, W2, bq, bk, bv,
                                      x, encW, encB,
                                      Bqkv, Bwo, Bw1, Bw2, bqkv, h);

  for (int l = 0; l < 2; ++l) {
    gemm_bt_wide<3><<<dim3(12, 150), 512, 0, stream>>>(
        h, 1024, Bqkv + (size_t)l * 3145728, bqkv + l * 3072, nullptr, 0, qkv, 3072);
    attn_mfma<<<dim3(5, 512), 256, 0, stream>>>(qkv, abuf);
    gemm_bt_wide<1><<<dim3(4, 150), 512, 0, stream>>>(
        abuf, 1024, Bwo + (size_t)l * 1048576, bo + l * 1024, h, 1024, ybuf, 3072);
    ln_kernel<<<19200, 256, 0, stream>>>(ybuf, 3072, ln1w + l * 1024, ln1b + l * 1024, x1, 3072);
    gemm_bt_wide<2><<<dim3(4, 150), 512, 0, stream>>>(
        x1, 3072, Bw2 + (size_t)l * 1048576, b2 + l * 1024, nullptr, 0, mid, 3072);
    gemm_bt_wide<1><<<dim3(4, 150), 512, 0, stream>>>(
        mid, 3072, Bw1 + (size_t)l * 1048576, b1 + l * 1024, x1, 3072, y2, 1024);
    ln_kernel<<<19200, 256, 0, stream>>>(y2, 1024, ln2w + l * 1024, ln2b + l * 1024, h, 1024);
  }
  out_kernel<<<4800, 256, 0, stream>>>(h, outW, outB, out);
}